// Round 7
// baseline (263.921 us; speedup 1.0000x reference)
//
#include <hip/hip_runtime.h>
#include <hip/hip_bf16.h>

// ---------------------------------------------------------------------------
// GCNWithSelfAttention: GCNConv -> MHA(8 heads) -> ReLU -> Linear
// B=4, N=2048, Din=256, H=512, nh=8, dh=64, E=65536, Dout=256.
// Full f16-MFMA chain. Flash: S^T register-P, K=32 PV via sigma-permuted V,
// 2 q-blocks/wave, K-SPLIT x2 (exact combine: no-max softmax partials add).
// ---------------------------------------------------------------------------

#define NN 2048
#define HH 512
#define NHEAD 8
#define DH 64

typedef _Float16 f16;
typedef __attribute__((ext_vector_type(2))) _Float16 f16x2;
typedef __attribute__((ext_vector_type(4))) _Float16 f16x4;
typedef __attribute__((ext_vector_type(8))) _Float16 f16x8;
typedef __attribute__((ext_vector_type(4))) float f32x4;

#define GLOAD_LDS16(g, l)                                              \
  __builtin_amdgcn_global_load_lds(                                    \
      (const __attribute__((address_space(1))) void*)(g),              \
      (__attribute__((address_space(3))) void*)(l), 16, 0, 0)

// ---------------- fused prep: wi/wo converts + deg/cursor init -------------

__global__ __launch_bounds__(256) void prep_cvt_kernel(const float* __restrict__ wi,
                                                       const float* __restrict__ wo,
                                                       f16* __restrict__ wi16,
                                                       f16* __restrict__ wo16,
                                                       float* __restrict__ deg,
                                                       int* __restrict__ cursor) {
  const int bid = blockIdx.x, t = threadIdx.x;
  if (bid < 768) {                       // wi: 1536*512 f32 = 196608 float4
    const int i = bid * 256 + t;
    const float4 v = ((const float4*)wi)[i];
    f16x4 o = { (f16)v.x, (f16)v.y, (f16)v.z, (f16)v.w };
    ((f16x4*)wi16)[i] = o;
  } else if (bid < 1024) {               // wo: 512*512 f32 = 65536 float4
    const int i = (bid - 768) * 256 + t;
    const float4 v = ((const float4*)wo)[i];
    f16x4 o = { (f16)v.x, (f16)v.y, (f16)v.z, (f16)v.w };
    ((f16x4*)wo16)[i] = o;
  } else {                               // deg/cursor init
    for (int i = t; i < NN; i += 256) { deg[i] = 1.0f; cursor[i] = 0; }
  }
}

// fused transpose-convert: wg [256,512]->[512,256], fcw [512,256]->[256,512]
__global__ __launch_bounds__(256) void prep_transpose_kernel(const float* __restrict__ wg,
                                                             const float* __restrict__ fcw,
                                                             f16* __restrict__ wg16t,
                                                             f16* __restrict__ fcw16t) {
  __shared__ float tbuf[32][33];
  const float* in;
  f16* outp;
  int R, C, bx, by;
  if (blockIdx.x < 128) { in = wg;  outp = wg16t;  R = 256; C = 512;
                          bx = blockIdx.x & 15; by = blockIdx.x >> 4; }
  else { int id = blockIdx.x - 128; in = fcw; outp = fcw16t; R = 512; C = 256;
         bx = id & 7; by = id >> 3; }
  const int c0 = bx * 32, r0 = by * 32;
  const int tx = threadIdx.x & 31, ty = threadIdx.x >> 5;
#pragma unroll
  for (int i = 0; i < 32; i += 8) tbuf[ty + i][tx] = in[(size_t)(r0 + ty + i) * C + c0 + tx];
  __syncthreads();
#pragma unroll
  for (int i = 0; i < 32; i += 8)
    outp[(size_t)(c0 + ty + i) * R + r0 + tx] = (f16)tbuf[tx][ty + i];
}

// ---------------- degree / CSR build ----------------

__global__ __launch_bounds__(256) void count_deg_kernel(const int* __restrict__ ei, int E,
                                                        float* __restrict__ deg) {
  int e = blockIdx.x * 256 + threadIdx.x;
  if (e < E) atomicAdd(&deg[ei[E + e]], 1.0f);  // dst row
}

__global__ __launch_bounds__(1024) void build_rowptr_kernel(const float* __restrict__ deg,
                                                            float* __restrict__ dinv,
                                                            int* __restrict__ rowptr) {
  __shared__ int a[NN];
  __shared__ int bbuf[NN];
  const int t = threadIdx.x;
  for (int i = t; i < NN; i += 1024) {
    float dg = deg[i];
    a[i] = (int)dg - 1;
    dinv[i] = rsqrtf(dg);
  }
  __syncthreads();
  int* src = a;
  int* dst = bbuf;
  for (int off = 1; off < NN; off <<= 1) {
    for (int i = t; i < NN; i += 1024) {
      int v = src[i];
      if (i >= off) v += src[i - off];
      dst[i] = v;
    }
    __syncthreads();
    int* tmp = src; src = dst; dst = tmp;
  }
  for (int i = t; i < NN; i += 1024) rowptr[i + 1] = src[i];
  if (t == 0) rowptr[0] = 0;
}

__global__ __launch_bounds__(256) void fill_csr_kernel(const int* __restrict__ ei, int E,
                                                       const int* __restrict__ rowptr,
                                                       int* __restrict__ cursor,
                                                       int* __restrict__ csr_src) {
  int e = blockIdx.x * 256 + threadIdx.x;
  if (e < E) {
    int s = ei[e];
    int d = ei[E + e];
    int pos = atomicAdd(&cursor[d], 1);
    csr_src[rowptr[d] + pos] = s;
  }
}

// ---------------- f16 MFMA GEMM: C[M,N] = A[M,K] * Bt[N,K]^T (+bias)(+relu) -
// MTxN128 tile, BK=32, 256 thr = 4 waves; MT=128: wave=64x64 (4x4 mfma),
// MT=64: wave=32x64 (2x4). OUTMODE: 0 f32 [M,N]; 1 f16 [M,N]; 2 qkv split.
// AF32: A is f32, converted during staging.

template <int OUTMODE, bool BIAS, bool RELU, bool AF32, int MT = 128>
__global__ __launch_bounds__(256) void mfma_gemm_kernel(
    const void* __restrict__ Ap, const f16* __restrict__ Bt,
    const float* __restrict__ bias, void* __restrict__ Cout,
    int M, int N, int K,
    f16* __restrict__ q_out, f16* __restrict__ k_out, f16* __restrict__ v_out) {
  constexpr int MI = MT / 32;  // 16-row blocks per wave in M
  __shared__ f16 As[MT * 32];
  __shared__ f16 Bs[128 * 32];
  const int tid = threadIdx.x;
  const int wave = tid >> 6, lane = tid & 63;
  const int quad = lane >> 4, l16 = lane & 15;
  const int m0 = blockIdx.y * MT, n0 = blockIdx.x * 128;
  const int moff = (wave >> 1) * (MI * 16), noff = (wave & 1) * 64;

  f32x4 acc[MI][4];
#pragma unroll
  for (int i = 0; i < MI; ++i)
#pragma unroll
    for (int j = 0; j < 4; ++j) acc[i][j] = (f32x4){0.f, 0.f, 0.f, 0.f};

  const int rpw = MT / 4;  // A rows staged per wave
  const int srowA = rpw * wave + (lane >> 2);
  const int srowB = 32 * wave + (lane >> 2);
  const int kch = (lane & 3) * 8;
  const f16* Ag = (const f16*)Ap + (size_t)(m0 + srowA) * K + kch;
  const float* Ag32 = (const float*)Ap + (size_t)(m0 + srowA) * K + kch;
  const f16* Bg = Bt + (size_t)(n0 + srowB) * K + kch;
  f16* As_w = &As[(rpw * wave) * 32];
  f16* Bs_w = &Bs[(32 * wave) * 32];

  for (int k0 = 0; k0 < K; k0 += 32) {
    __syncthreads();
    if (AF32) {
#pragma unroll
      for (int t = 0; t < 2; ++t) {
        const float* g = Ag32 + k0 + (size_t)(16 * t) * K;
        const float4 u0 = *(const float4*)g;
        const float4 u1 = *(const float4*)(g + 4);
        f16x8 o = { (f16)u0.x, (f16)u0.y, (f16)u0.z, (f16)u0.w,
                    (f16)u1.x, (f16)u1.y, (f16)u1.z, (f16)u1.w };
        *(f16x8*)&As[(srowA + 16 * t) * 32 + kch] = o;
      }
    } else {
      GLOAD_LDS16(Ag + k0, As_w);
      if (MT == 128) GLOAD_LDS16(Ag + k0 + (size_t)16 * K, As_w + 16 * 32);
    }
    GLOAD_LDS16(Bg + k0, Bs_w);
    GLOAD_LDS16(Bg + k0 + (size_t)16 * K, Bs_w + 16 * 32);
    __syncthreads();
    f16x8 af[MI], bf[4];
#pragma unroll
    for (int m16 = 0; m16 < MI; ++m16)
      af[m16] = *(const f16x8*)&As[(moff + m16 * 16 + l16) * 32 + quad * 8];
#pragma unroll
    for (int n16 = 0; n16 < 4; ++n16)
      bf[n16] = *(const f16x8*)&Bs[(noff + n16 * 16 + l16) * 32 + quad * 8];
#pragma unroll
    for (int m16 = 0; m16 < MI; ++m16)
#pragma unroll
      for (int n16 = 0; n16 < 4; ++n16)
        acc[m16][n16] =
            __builtin_amdgcn_mfma_f32_16x16x32_f16(af[m16], bf[n16], acc[m16][n16], 0, 0, 0);
  }

  float bv[4];
#pragma unroll
  for (int n16 = 0; n16 < 4; ++n16)
    bv[n16] = BIAS ? bias[n0 + noff + n16 * 16 + l16] : 0.f;

  if (OUTMODE == 2) {
    const int hblk = (n0 >> 6) + (wave & 1);
    const int which = hblk >> 3, h = hblk & 7;
    f16* dst = (which == 0) ? q_out : (which == 1) ? k_out : v_out;
    const float scale = (which == 0) ? 0.125f : 1.0f;
#pragma unroll
    for (int m16 = 0; m16 < MI; ++m16) {
#pragma unroll
      for (int r = 0; r < 4; ++r) {
        const int m = m0 + moff + m16 * 16 + quad * 4 + r;
        const int b = m >> 11, ns = m & 2047;
        f16* row = dst + ((size_t)(b * 8 + h) * NN + ns) * DH;
#pragma unroll
        for (int n16 = 0; n16 < 4; ++n16) {
          const int d = n16 * 16 + l16;
          row[d] = (f16)((acc[m16][n16][r] + bv[n16]) * scale);
        }
      }
    }
  } else {
#pragma unroll
    for (int m16 = 0; m16 < MI; ++m16) {
#pragma unroll
      for (int r = 0; r < 4; ++r) {
        const size_t row = (size_t)(m0 + moff + m16 * 16 + quad * 4 + r) * N;
#pragma unroll
        for (int n16 = 0; n16 < 4; ++n16) {
          const int col = n0 + noff + n16 * 16 + l16;
          float v = acc[m16][n16][r] + bv[n16];
          if (RELU) v = fmaxf(v, 0.f);
          if (OUTMODE == 0) ((float*)Cout)[row + col] = v;
          else ((f16*)Cout)[row + col] = (f16)v;
        }
      }
    }
  }
}

// ---------------- GCN aggregation (CSR gather; thread = batch x octet) -----

__global__ __launch_bounds__(256) void gcn_aggregate_kernel(const f16* __restrict__ xl,
                                                            const float* __restrict__ dinv,
                                                            const int* __restrict__ rowptr,
                                                            const int* __restrict__ csr_src,
                                                            const float* __restrict__ b_gcn,
                                                            f16* __restrict__ out) {
  __shared__ int s_src[256];
  __shared__ float s_dv[256];
  const int i = blockIdx.x;            // node, shared by all 4 batches
  const int tid = threadIdx.x;
  const int b = tid >> 6;              // batch
  const int f = (tid & 63) * 8;        // feature octet
  const float dv_i = dinv[i];
  const f16* xb = xl + (size_t)b * NN * HH;
  float acc[8];
  {
    const f16x8 self = *(const f16x8*)&xb[(size_t)i * HH + f];
#pragma unroll
    for (int c = 0; c < 8; ++c) acc[c] = (float)self[c] * dv_i;
  }
  const int beg = rowptr[i], end = rowptr[i + 1];
  for (int c0 = beg; c0 < end; c0 += 256) {
    const int cnt = min(256, end - c0);
    __syncthreads();
    if (tid < cnt) {
      int s = csr_src[c0 + tid];
      s_src[tid] = s;
      s_dv[tid] = dinv[s];
    }
    __syncthreads();
    for (int t = 0; t < cnt; ++t) {
      const f16x8 v = *(const f16x8*)&xb[(size_t)s_src[t] * HH + f];
      const float w = s_dv[t];
#pragma unroll
      for (int c = 0; c < 8; ++c) acc[c] = fmaf((float)v[c], w, acc[c]);
    }
  }
  const float4 bg0 = *(const float4*)&b_gcn[f];
  const float4 bg1 = *(const float4*)&b_gcn[f + 4];
  f16x8 o;
  o[0] = (f16)(acc[0] * dv_i + bg0.x);
  o[1] = (f16)(acc[1] * dv_i + bg0.y);
  o[2] = (f16)(acc[2] * dv_i + bg0.z);
  o[3] = (f16)(acc[3] * dv_i + bg0.w);
  o[4] = (f16)(acc[4] * dv_i + bg1.x);
  o[5] = (f16)(acc[5] * dv_i + bg1.y);
  o[6] = (f16)(acc[6] * dv_i + bg1.z);
  o[7] = (f16)(acc[7] * dv_i + bg1.w);
  *(f16x8*)&out[((size_t)b * NN + i) * HH + f] = o;
}

// ---------------- flash attention v4: K-split x2 ----------------
// Q/K/V: f16 [bh][n][64], Q pre-scaled. Block = 4 waves, q-tile 128 (wave w
// owns q-16-blocks w, w+4). blockIdx.z = K-half (8 of 16 K-tiles each).
// No-max softmax -> partials combine exactly in a later pass:
//   attn = (O0 + O1) / (l0 + l1)
// Partial O (unnormalized, f16) -> Op[kh]; partial l (f32) -> Lp[kh].

__global__ __launch_bounds__(256) void flash_attn_f16_kernel(const f16* __restrict__ Qb,
                                                             const f16* __restrict__ Kb,
                                                             const f16* __restrict__ Vb,
                                                             f16* __restrict__ Op,
                                                             float* __restrict__ Lp) {
  const int LDK = 72;   // dword stride 36 -> b128 frag reads uniform-8 (floor)
  const int LDV = 136;  // dword stride 68 -> b128 frag reads uniform-8 (floor)
  __shared__ f16 Ks[128 * LDK];   // 18.4 KB
  __shared__ f16 Vt[64 * LDV];    // 17.4 KB
  const int tid = threadIdx.x;
  const int wave = tid >> 6, lane = tid & 63;
  const int quad = lane >> 4, l16 = lane & 15;
  const int n0 = blockIdx.x * 128;
  const int bh = blockIdx.y;
  const int kh = blockIdx.z;
  const int b = bh >> 3, h = bh & 7;
  const f16* kb = Kb + (size_t)bh * NN * DH;
  const f16* vb = Vb + (size_t)bh * NN * DH;

  f16x8 aq[2][2];
#pragma unroll
  for (int g = 0; g < 2; ++g) {
    const f16* qf = Qb + ((size_t)bh * NN + n0 + (wave + 4 * g) * 16 + l16) * DH + quad * 8;
    aq[g][0] = *(const f16x8*)qf;
    aq[g][1] = *(const f16x8*)(qf + 32);
  }

  float l_part[2] = {0.f, 0.f};
  f32x4 acc_o[2][4];
#pragma unroll
  for (int g = 0; g < 2; ++g)
#pragma unroll
    for (int n16 = 0; n16 < 4; ++n16) acc_o[g][n16] = (f32x4){0.f, 0.f, 0.f, 0.f};

  const int vdg = tid & 15, jbb = tid >> 4;

  for (int kt = kh * 8; kt < kh * 8 + 8; ++kt) {
    const int k0 = kt * 128;
    __syncthreads();
    // K stage: 128 rows x 8 b128 chunks
#pragma unroll
    for (int i = 0; i < 4; ++i) {
      int idx = tid + 256 * i;
      int r = idx >> 3, koff = (idx & 7) * 8;
      *(f16x8*)&Ks[r * LDK + koff] = *(const f16x8*)(kb + (size_t)(k0 + r) * DH + koff);
    }
    // V stage transposed + sigma-permuted
#pragma unroll
    for (int cc = 0; cc < 2; ++cc) {
      const int jb = jbb + 16 * cc;
      const int sb4 = (jb >> 3) * 32 + (jb & 3) * 8 + ((jb >> 2) & 1) * 4;
      f16x4 vv[4];
#pragma unroll
      for (int i = 0; i < 4; ++i)
        vv[i] = *(const f16x4*)(vb + (size_t)(k0 + jb * 4 + i) * DH + vdg * 4);
#pragma unroll
      for (int c = 0; c < 4; ++c) {
        f16x4 o = { vv[0][c], vv[1][c], vv[2][c], vv[3][c] };
        *(f16x4*)&Vt[(vdg * 4 + c) * LDV + sb4] = o;
      }
    }
    __syncthreads();
    // per 32-col group p: 2 S^T tiles x 2 q-blocks -> register P -> K=32 PV
#pragma unroll
    for (int p = 0; p < 4; ++p) {
      f32x4 sA[2][2];  // [g][t]
#pragma unroll
      for (int t = 0; t < 2; ++t) {
        const f16x8 ak0 = *(const f16x8*)&Ks[(p * 32 + t * 16 + l16) * LDK + quad * 8];
        const f16x8 ak1 = *(const f16x8*)&Ks[(p * 32 + t * 16 + l16) * LDK + quad * 8 + 32];
#pragma unroll
        for (int g = 0; g < 2; ++g) {
          f32x4 s = {0.f, 0.f, 0.f, 0.f};
          s = __builtin_amdgcn_mfma_f32_16x16x32_f16(ak0, aq[g][0], s, 0, 0, 0);
          s = __builtin_amdgcn_mfma_f32_16x16x32_f16(ak1, aq[g][1], s, 0, 0, 0);
          sA[g][t] = s;
        }
      }
      f16x8 bvv[4];
#pragma unroll
      for (int n16 = 0; n16 < 4; ++n16)
        bvv[n16] = *(const f16x8*)&Vt[(n16 * 16 + l16) * LDV + p * 32 + quad * 8];
#pragma unroll
      for (int g = 0; g < 2; ++g) {
        f16x8 ap;
        float sum = 0.f;
#pragma unroll
        for (int t = 0; t < 2; ++t)
#pragma unroll
          for (int r = 0; r < 4; ++r) {
            const float e = __expf(sA[g][t][r]);
            sum += e;
            ap[t * 4 + r] = (f16)e;
          }
        l_part[g] += sum;
#pragma unroll
        for (int n16 = 0; n16 < 4; ++n16)
          acc_o[g][n16] = __builtin_amdgcn_mfma_f32_16x16x32_f16(ap, bvv[n16], acc_o[g][n16], 0, 0, 0);
      }
    }
  }
  // partial outputs: unnormalized O (f16), partial l (f32)
  f16* ohalf = Op + (size_t)kh * 4 * NN * HH;
#pragma unroll
  for (int g = 0; g < 2; ++g) {
    float lp = l_part[g];
    lp += __shfl_xor(lp, 16);
    lp += __shfl_xor(lp, 32);
    const int qrow = n0 + (wave + 4 * g) * 16;
    if (quad == 0) Lp[(size_t)(kh * 32 + bh) * NN + qrow + l16] = lp;
    f16* obase = ohalf + ((size_t)b * NN + qrow) * HH + h * DH;
#pragma unroll
    for (int r = 0; r < 4; ++r)
#pragma unroll
      for (int n16 = 0; n16 < 4; ++n16)
        obase[(size_t)(quad * 4 + r) * HH + n16 * 16 + l16] = (f16)acc_o[g][n16][r];
  }
}

// combine: attn = (O0 + O1) / (l0 + l1)
__global__ __launch_bounds__(256) void attn_combine_kernel(const f16* __restrict__ Op,
                                                           const float* __restrict__ Lp,
                                                           f16* __restrict__ attn) {
  const int idx = blockIdx.x * 256 + threadIdx.x;   // 8192 rows x 128 col4s
  const int row = idx >> 7, c4 = (idx & 127) * 4;
  const int h = c4 >> 6;
  const int b = row >> 11, n = row & 2047;
  const int bh = b * 8 + h;
  const float l = Lp[(size_t)bh * NN + n] + Lp[(size_t)(32 + bh) * NN + n];
  const float inv = 1.0f / l;
  const f16x4 a0 = *(const f16x4*)&Op[(size_t)row * HH + c4];
  const f16x4 a1 = *(const f16x4*)&Op[(size_t)(4 * NN + row) * HH + c4];
  f16x4 o;
#pragma unroll
  for (int c = 0; c < 4; ++c) o[c] = (f16)(((float)a0[c] + (float)a1[c]) * inv);
  *(f16x4*)&attn[(size_t)row * HH + c4] = o;
}

// ---------------------------------------------------------------------------

extern "C" void kernel_launch(void* const* d_in, const int* in_sizes, int n_in,
                              void* d_out, int out_size, void* d_ws, size_t ws_size,
                              hipStream_t stream) {
  const float* x     = (const float*)d_in[0];
  const int*   ei    = (const int*)d_in[1];
  const float* W_gcn = (const float*)d_in[2];
  const float* b_gcn = (const float*)d_in[3];
  const float* wi    = (const float*)d_in[4];
  const float* bi    = (const float*)d_in[5];
  const float* wo    = (const float*)d_in[6];
  const float* bo    = (const float*)d_in[7];
  const float* fcw   = (const float*)d_in[8];
  const float* fcb   = (const float*)d_in[9];
  float* out = (float*)d_out;
  const int E = in_sizes[1] / 2;  // 65536
  const int M = 4 * NN;           // 8192 rows

  char* wsb = (char*)d_ws;
  const size_t MB = 1u << 20;
  f16* xl16   = (f16*)(wsb + 4 * MB);         // 8 MB (dead after aggregate)
  f16* hb16   = (f16*)(wsb + 12 * MB);        // 8 MB (dead after qkv gemm)
  f16* Opart  = (f16*)(wsb + 4 * MB);         // 16 MB, overlays xl16+hb16
  f16* Qb     = (f16*)(wsb + 20 * MB);        // 8 MB
  f16* Kb     = (f16*)(wsb + 28 * MB);        // 8 MB
  f16* Vb     = (f16*)(wsb + 36 * MB);        // 8 MB
  f16* attn16 = (f16*)(wsb + 44 * MB);        // 8 MB
  f16* proj16 = (f16*)(wsb + 52 * MB);        // 8 MB
  f16* wi16   = (f16*)(wsb + 60 * MB);        // 1.5 MB  [1536,512] (n,k)
  f16* wo16   = (f16*)(wsb + 62 * MB);        // 0.5 MB  [512,512]  (n,k)
  f16* wg16t  = (f16*)(wsb + 63 * MB);        // 0.25 MB [512,256]  (n,k)
  f16* fcw16t = (f16*)(wsb + 64 * MB);        // 0.25 MB [256,512]  (n,k)
  float* deg  = (float*)(wsb + 65 * MB);
  float* dinv = deg + NN;
  int* rowptr = (int*)(dinv + NN);
  int* cursor = rowptr + 2080;
  int* csr    = cursor + NN;                  // E ints
  float* Lpart = (float*)(wsb + 66 * MB);     // 2*32*2048 f32 = 512 KB

  // fused prep: converts + deg/cursor init (2 kernels)
  prep_cvt_kernel<<<1025, 256, 0, stream>>>(wi, wo, wi16, wo16, deg, cursor);
  prep_transpose_kernel<<<256, 256, 0, stream>>>(W_gcn, fcw, wg16t, fcw16t);

  // CSR build
  count_deg_kernel<<<(E + 255) / 256, 256, 0, stream>>>(ei, E, deg);
  build_rowptr_kernel<<<1, 1024, 0, stream>>>(deg, dinv, rowptr);
  fill_csr_kernel<<<(E + 255) / 256, 256, 0, stream>>>(ei, E, rowptr, cursor, csr);

  // xl = x @ W_gcn -> f16 (A staged f32->f16 in-kernel)  [8192,512]
  mfma_gemm_kernel<1, false, false, true><<<dim3(4, 64), 256, 0, stream>>>(
      x, wg16t, nullptr, xl16, M, 512, 256, nullptr, nullptr, nullptr);
  // h = GCN aggregate + b_gcn -> f16   [8192,512]
  gcn_aggregate_kernel<<<NN, 256, 0, stream>>>(xl16, dinv, rowptr, csr, b_gcn, hb16);
  // qkv = h @ wi^T + bi -> Q/K/V split f16 [bh][n][64], Q scaled
  mfma_gemm_kernel<2, true, false, false><<<dim3(12, 64), 256, 0, stream>>>(
      hb16, wi16, bi, nullptr, M, 1536, 512, Qb, Kb, Vb);
  // attention partials (K-split x2) -> Opart/Lpart
  flash_attn_f16_kernel<<<dim3(NN / 128, 32, 2), 256, 0, stream>>>(Qb, Kb, Vb, Opart, Lpart);
  // exact combine -> attn16
  attn_combine_kernel<<<M * (HH / 4) / 256, 256, 0, stream>>>(Opart, Lpart, attn16);
  // proj = relu(attn @ wo^T + bo) -> f16
  mfma_gemm_kernel<1, true, true, false><<<dim3(4, 64), 256, 0, stream>>>(
      attn16, wo16, bo, proj16, M, 512, 512, nullptr, nullptr, nullptr);
  // out = proj @ fc_w + fc_b -> f32    [8192,256]  (MT=64: 256 blocks)
  mfma_gemm_kernel<0, true, false, false, 64><<<dim3(2, 128), 256, 0, stream>>>(
      proj16, fcw16t, fcb, out, M, 256, 512, nullptr, nullptr, nullptr);
}

// Round 9
// 262.025 us; speedup vs baseline: 1.0072x; 1.0072x over previous
//
#include <hip/hip_runtime.h>
#include <hip/hip_bf16.h>

// ---------------------------------------------------------------------------
// GCNWithSelfAttention: GCNConv -> MHA(8 heads) -> ReLU -> Linear
// B=4, N=2048, Din=256, H=512, nh=8, dh=64, E=65536, Dout=256.
// Full f16-MFMA chain. Flash: S^T register-P, K=32 PV via sigma-permuted V,
// 2 q-blocks/wave, exp2-folded scale (Q *= 0.125*log2e), pkrtz P packing.
// ---------------------------------------------------------------------------

#define NN 2048
#define HH 512
#define NHEAD 8
#define DH 64

typedef _Float16 f16;
typedef __attribute__((ext_vector_type(2))) _Float16 f16x2;
typedef __attribute__((ext_vector_type(4))) _Float16 f16x4;
typedef __attribute__((ext_vector_type(8))) _Float16 f16x8;
typedef __attribute__((ext_vector_type(2))) __fp16 fp16v2;   // pkrtz return type
typedef __attribute__((ext_vector_type(4))) float f32x4;

#define GLOAD_LDS16(g, l)                                              \
  __builtin_amdgcn_global_load_lds(                                    \
      (const __attribute__((address_space(1))) void*)(g),              \
      (__attribute__((address_space(3))) void*)(l), 16, 0, 0)

// ---------------- fused prep: wi/wo converts + deg/cursor init -------------

__global__ __launch_bounds__(256) void prep_cvt_kernel(const float* __restrict__ wi,
                                                       const float* __restrict__ wo,
                                                       f16* __restrict__ wi16,
                                                       f16* __restrict__ wo16,
                                                       float* __restrict__ deg,
                                                       int* __restrict__ cursor) {
  const int bid = blockIdx.x, t = threadIdx.x;
  if (bid < 768) {                       // wi: 1536*512 f32 = 196608 float4
    const int i = bid * 256 + t;
    const float4 v = ((const float4*)wi)[i];
    f16x4 o = { (f16)v.x, (f16)v.y, (f16)v.z, (f16)v.w };
    ((f16x4*)wi16)[i] = o;
  } else if (bid < 1024) {               // wo: 512*512 f32 = 65536 float4
    const int i = (bid - 768) * 256 + t;
    const float4 v = ((const float4*)wo)[i];
    f16x4 o = { (f16)v.x, (f16)v.y, (f16)v.z, (f16)v.w };
    ((f16x4*)wo16)[i] = o;
  } else {                               // deg/cursor init
    for (int i = t; i < NN; i += 256) { deg[i] = 1.0f; cursor[i] = 0; }
  }
}

// fused transpose-convert: wg [256,512]->[512,256], fcw [512,256]->[256,512]
__global__ __launch_bounds__(256) void prep_transpose_kernel(const float* __restrict__ wg,
                                                             const float* __restrict__ fcw,
                                                             f16* __restrict__ wg16t,
                                                             f16* __restrict__ fcw16t) {
  __shared__ float tbuf[32][33];
  const float* in;
  f16* outp;
  int R, C, bx, by;
  if (blockIdx.x < 128) { in = wg;  outp = wg16t;  R = 256; C = 512;
                          bx = blockIdx.x & 15; by = blockIdx.x >> 4; }
  else { int id = blockIdx.x - 128; in = fcw; outp = fcw16t; R = 512; C = 256;
         bx = id & 7; by = id >> 3; }
  const int c0 = bx * 32, r0 = by * 32;
  const int tx = threadIdx.x & 31, ty = threadIdx.x >> 5;
#pragma unroll
  for (int i = 0; i < 32; i += 8) tbuf[ty + i][tx] = in[(size_t)(r0 + ty + i) * C + c0 + tx];
  __syncthreads();
#pragma unroll
  for (int i = 0; i < 32; i += 8)
    outp[(size_t)(c0 + ty + i) * R + r0 + tx] = (f16)tbuf[tx][ty + i];
}

// ---------------- degree / CSR build ----------------

__global__ __launch_bounds__(256) void count_deg_kernel(const int* __restrict__ ei, int E,
                                                        float* __restrict__ deg) {
  int e = blockIdx.x * 256 + threadIdx.x;
  if (e < E) atomicAdd(&deg[ei[E + e]], 1.0f);  // dst row
}

__global__ __launch_bounds__(1024) void build_rowptr_kernel(const float* __restrict__ deg,
                                                            float* __restrict__ dinv,
                                                            int* __restrict__ rowptr) {
  __shared__ int a[NN];
  __shared__ int bbuf[NN];
  const int t = threadIdx.x;
  for (int i = t; i < NN; i += 1024) {
    float dg = deg[i];
    a[i] = (int)dg - 1;
    dinv[i] = rsqrtf(dg);
  }
  __syncthreads();
  int* src = a;
  int* dst = bbuf;
  for (int off = 1; off < NN; off <<= 1) {
    for (int i = t; i < NN; i += 1024) {
      int v = src[i];
      if (i >= off) v += src[i - off];
      dst[i] = v;
    }
    __syncthreads();
    int* tmp = src; src = dst; dst = tmp;
  }
  for (int i = t; i < NN; i += 1024) rowptr[i + 1] = src[i];
  if (t == 0) rowptr[0] = 0;
}

__global__ __launch_bounds__(256) void fill_csr_kernel(const int* __restrict__ ei, int E,
                                                       const int* __restrict__ rowptr,
                                                       int* __restrict__ cursor,
                                                       int* __restrict__ csr_src) {
  int e = blockIdx.x * 256 + threadIdx.x;
  if (e < E) {
    int s = ei[e];
    int d = ei[E + e];
    int pos = atomicAdd(&cursor[d], 1);
    csr_src[rowptr[d] + pos] = s;
  }
}

// ---------------- f16 MFMA GEMM: C[M,N] = A[M,K] * Bt[N,K]^T (+bias)(+relu) -
// MTxN128 tile, BK=32, 256 thr = 4 waves; MT=128: wave=64x64 (4x4 mfma),
// MT=64: wave=32x64 (2x4). OUTMODE: 0 f32 [M,N]; 1 f16 [M,N]; 2 qkv split.
// AF32: A is f32, converted during staging.

template <int OUTMODE, bool BIAS, bool RELU, bool AF32, int MT = 128>
__global__ __launch_bounds__(256) void mfma_gemm_kernel(
    const void* __restrict__ Ap, const f16* __restrict__ Bt,
    const float* __restrict__ bias, void* __restrict__ Cout,
    int M, int N, int K,
    f16* __restrict__ q_out, f16* __restrict__ k_out, f16* __restrict__ v_out) {
  constexpr int MI = MT / 32;  // 16-row blocks per wave in M
  __shared__ f16 As[MT * 32];
  __shared__ f16 Bs[128 * 32];
  const int tid = threadIdx.x;
  const int wave = tid >> 6, lane = tid & 63;
  const int quad = lane >> 4, l16 = lane & 15;
  const int m0 = blockIdx.y * MT, n0 = blockIdx.x * 128;
  const int moff = (wave >> 1) * (MI * 16), noff = (wave & 1) * 64;

  f32x4 acc[MI][4];
#pragma unroll
  for (int i = 0; i < MI; ++i)
#pragma unroll
    for (int j = 0; j < 4; ++j) acc[i][j] = (f32x4){0.f, 0.f, 0.f, 0.f};

  const int rpw = MT / 4;  // A rows staged per wave
  const int srowA = rpw * wave + (lane >> 2);
  const int srowB = 32 * wave + (lane >> 2);
  const int kch = (lane & 3) * 8;
  const f16* Ag = (const f16*)Ap + (size_t)(m0 + srowA) * K + kch;
  const float* Ag32 = (const float*)Ap + (size_t)(m0 + srowA) * K + kch;
  const f16* Bg = Bt + (size_t)(n0 + srowB) * K + kch;
  f16* As_w = &As[(rpw * wave) * 32];
  f16* Bs_w = &Bs[(32 * wave) * 32];

  for (int k0 = 0; k0 < K; k0 += 32) {
    __syncthreads();
    if (AF32) {
#pragma unroll
      for (int t = 0; t < (MT == 128 ? 2 : 1); ++t) {
        const float* g = Ag32 + k0 + (size_t)(16 * t) * K;
        const float4 u0 = *(const float4*)g;
        const float4 u1 = *(const float4*)(g + 4);
        f16x8 o = { (f16)u0.x, (f16)u0.y, (f16)u0.z, (f16)u0.w,
                    (f16)u1.x, (f16)u1.y, (f16)u1.z, (f16)u1.w };
        *(f16x8*)&As[(srowA + 16 * t) * 32 + kch] = o;
      }
    } else {
      GLOAD_LDS16(Ag + k0, As_w);
      if (MT == 128) GLOAD_LDS16(Ag + k0 + (size_t)16 * K, As_w + 16 * 32);
    }
    GLOAD_LDS16(Bg + k0, Bs_w);
    GLOAD_LDS16(Bg + k0 + (size_t)16 * K, Bs_w + 16 * 32);
    __syncthreads();
    f16x8 af[MI], bf[4];
#pragma unroll
    for (int m16 = 0; m16 < MI; ++m16)
      af[m16] = *(const f16x8*)&As[(moff + m16 * 16 + l16) * 32 + quad * 8];
#pragma unroll
    for (int n16 = 0; n16 < 4; ++n16)
      bf[n16] = *(const f16x8*)&Bs[(noff + n16 * 16 + l16) * 32 + quad * 8];
#pragma unroll
    for (int m16 = 0; m16 < MI; ++m16)
#pragma unroll
      for (int n16 = 0; n16 < 4; ++n16)
        acc[m16][n16] =
            __builtin_amdgcn_mfma_f32_16x16x32_f16(af[m16], bf[n16], acc[m16][n16], 0, 0, 0);
  }

  float bv[4];
#pragma unroll
  for (int n16 = 0; n16 < 4; ++n16)
    bv[n16] = BIAS ? bias[n0 + noff + n16 * 16 + l16] : 0.f;

  if (OUTMODE == 2) {
    const int hblk = (n0 >> 6) + (wave & 1);
    const int which = hblk >> 3, h = hblk & 7;
    f16* dst = (which == 0) ? q_out : (which == 1) ? k_out : v_out;
    // Q pre-scale folds dh^-0.5 AND log2(e) so flash can use bare exp2.
    const float scale = (which == 0) ? 0.125f * 1.44269504f : 1.0f;
#pragma unroll
    for (int m16 = 0; m16 < MI; ++m16) {
#pragma unroll
      for (int r = 0; r < 4; ++r) {
        const int m = m0 + moff + m16 * 16 + quad * 4 + r;
        const int b = m >> 11, ns = m & 2047;
        f16* row = dst + ((size_t)(b * 8 + h) * NN + ns) * DH;
#pragma unroll
        for (int n16 = 0; n16 < 4; ++n16) {
          const int d = n16 * 16 + l16;
          row[d] = (f16)((acc[m16][n16][r] + bv[n16]) * scale);
        }
      }
    }
  } else {
#pragma unroll
    for (int m16 = 0; m16 < MI; ++m16) {
#pragma unroll
      for (int r = 0; r < 4; ++r) {
        const size_t row = (size_t)(m0 + moff + m16 * 16 + quad * 4 + r) * N;
#pragma unroll
        for (int n16 = 0; n16 < 4; ++n16) {
          const int col = n0 + noff + n16 * 16 + l16;
          float v = acc[m16][n16][r] + bv[n16];
          if (RELU) v = fmaxf(v, 0.f);
          if (OUTMODE == 0) ((float*)Cout)[row + col] = v;
          else ((f16*)Cout)[row + col] = (f16)v;
        }
      }
    }
  }
}

// ---------------- GCN aggregation (CSR gather; thread = batch x octet) -----

__global__ __launch_bounds__(256) void gcn_aggregate_kernel(const f16* __restrict__ xl,
                                                            const float* __restrict__ dinv,
                                                            const int* __restrict__ rowptr,
                                                            const int* __restrict__ csr_src,
                                                            const float* __restrict__ b_gcn,
                                                            f16* __restrict__ out) {
  __shared__ int s_src[256];
  __shared__ float s_dv[256];
  const int i = blockIdx.x;            // node, shared by all 4 batches
  const int tid = threadIdx.x;
  const int b = tid >> 6;              // batch
  const int f = (tid & 63) * 8;        // feature octet
  const float dv_i = dinv[i];
  const f16* xb = xl + (size_t)b * NN * HH;
  float acc[8];
  {
    const f16x8 self = *(const f16x8*)&xb[(size_t)i * HH + f];
#pragma unroll
    for (int c = 0; c < 8; ++c) acc[c] = (float)self[c] * dv_i;
  }
  const int beg = rowptr[i], end = rowptr[i + 1];
  for (int c0 = beg; c0 < end; c0 += 256) {
    const int cnt = min(256, end - c0);
    __syncthreads();
    if (tid < cnt) {
      int s = csr_src[c0 + tid];
      s_src[tid] = s;
      s_dv[tid] = dinv[s];
    }
    __syncthreads();
    for (int t = 0; t < cnt; ++t) {
      const f16x8 v = *(const f16x8*)&xb[(size_t)s_src[t] * HH + f];
      const float w = s_dv[t];
#pragma unroll
      for (int c = 0; c < 8; ++c) acc[c] = fmaf((float)v[c], w, acc[c]);
    }
  }
  const float4 bg0 = *(const float4*)&b_gcn[f];
  const float4 bg1 = *(const float4*)&b_gcn[f + 4];
  f16x8 o;
  o[0] = (f16)(acc[0] * dv_i + bg0.x);
  o[1] = (f16)(acc[1] * dv_i + bg0.y);
  o[2] = (f16)(acc[2] * dv_i + bg0.z);
  o[3] = (f16)(acc[3] * dv_i + bg0.w);
  o[4] = (f16)(acc[4] * dv_i + bg1.x);
  o[5] = (f16)(acc[5] * dv_i + bg1.y);
  o[6] = (f16)(acc[6] * dv_i + bg1.z);
  o[7] = (f16)(acc[7] * dv_i + bg1.w);
  *(f16x8*)&out[((size_t)b * NN + i) * HH + f] = o;
}

// ---------------- flash attention v5 (no K-split; exp2; pkrtz) -------------
// Q/K/V: f16 [bh][n][64]; Q pre-scaled by 0.125*log2e. Block = 4 waves,
// q-tile 128 (wave w owns q-16-blocks w, w+4). K-tile 128.
// S^T = K*Q^T (C col=l16=q-row, row=quad*4+r=k-col). P stays in registers.
// PV at K=32 via sigma-permuted V rows:
//   slot(k) = (k>>5)*32 + ((k>>2)&3)*8 + ((k>>4)&1)*4 + (k&3)

__global__ __launch_bounds__(256) void flash_attn_f16_kernel(const f16* __restrict__ Qb,
                                                             const f16* __restrict__ Kb,
                                                             const f16* __restrict__ Vb,
                                                             f16* __restrict__ out) {
  const int LDK = 72;   // dword stride 36 -> b128 frag reads uniform-8 (floor)
  const int LDV = 136;  // dword stride 68 -> b128 frag reads uniform-8 (floor)
  __shared__ f16 Ks[128 * LDK];   // 18.4 KB
  __shared__ f16 Vt[64 * LDV];    // 17.4 KB
  const int tid = threadIdx.x;
  const int wave = tid >> 6, lane = tid & 63;
  const int quad = lane >> 4, l16 = lane & 15;
  const int n0 = blockIdx.x * 128;
  const int bh = blockIdx.y;
  const int b = bh >> 3, h = bh & 7;
  const f16* kb = Kb + (size_t)bh * NN * DH;
  const f16* vb = Vb + (size_t)bh * NN * DH;

  f16x8 aq[2][2];
#pragma unroll
  for (int g = 0; g < 2; ++g) {
    const f16* qf = Qb + ((size_t)bh * NN + n0 + (wave + 4 * g) * 16 + l16) * DH + quad * 8;
    aq[g][0] = *(const f16x8*)qf;
    aq[g][1] = *(const f16x8*)(qf + 32);
  }

  float l_part[2] = {0.f, 0.f};
  f32x4 acc_o[2][4];
#pragma unroll
  for (int g = 0; g < 2; ++g)
#pragma unroll
    for (int n16 = 0; n16 < 4; ++n16) acc_o[g][n16] = (f32x4){0.f, 0.f, 0.f, 0.f};

  const int vdg = tid & 15, jbb = tid >> 4;

  for (int kt = 0; kt < NN / 128; ++kt) {
    const int k0 = kt * 128;
    __syncthreads();
    // K stage: 128 rows x 8 b128 chunks
#pragma unroll
    for (int i = 0; i < 4; ++i) {
      int idx = tid + 256 * i;
      int r = idx >> 3, koff = (idx & 7) * 8;
      *(f16x8*)&Ks[r * LDK + koff] = *(const f16x8*)(kb + (size_t)(k0 + r) * DH + koff);
    }
    // V stage transposed + sigma-permuted
#pragma unroll
    for (int cc = 0; cc < 2; ++cc) {
      const int jb = jbb + 16 * cc;
      const int sb4 = (jb >> 3) * 32 + (jb & 3) * 8 + ((jb >> 2) & 1) * 4;
      f16x4 vv[4];
#pragma unroll
      for (int i = 0; i < 4; ++i)
        vv[i] = *(const f16x4*)(vb + (size_t)(k0 + jb * 4 + i) * DH + vdg * 4);
#pragma unroll
      for (int c = 0; c < 4; ++c) {
        f16x4 o = { vv[0][c], vv[1][c], vv[2][c], vv[3][c] };
        *(f16x4*)&Vt[(vdg * 4 + c) * LDV + sb4] = o;
      }
    }
    __syncthreads();
    // per 32-col group p: 2 S^T tiles x 2 q-blocks -> register P -> K=32 PV
#pragma unroll
    for (int p = 0; p < 4; ++p) {
      f32x4 sA[2][2];  // [g][t]
#pragma unroll
      for (int t = 0; t < 2; ++t) {
        const f16x8 ak0 = *(const f16x8*)&Ks[(p * 32 + t * 16 + l16) * LDK + quad * 8];
        const f16x8 ak1 = *(const f16x8*)&Ks[(p * 32 + t * 16 + l16) * LDK + quad * 8 + 32];
#pragma unroll
        for (int g = 0; g < 2; ++g) {
          f32x4 s = {0.f, 0.f, 0.f, 0.f};
          s = __builtin_amdgcn_mfma_f32_16x16x32_f16(ak0, aq[g][0], s, 0, 0, 0);
          s = __builtin_amdgcn_mfma_f32_16x16x32_f16(ak1, aq[g][1], s, 0, 0, 0);
          sA[g][t] = s;
        }
      }
      f16x8 bvv[4];
#pragma unroll
      for (int n16 = 0; n16 < 4; ++n16)
        bvv[n16] = *(const f16x8*)&Vt[(n16 * 16 + l16) * LDV + p * 32 + quad * 8];
#pragma unroll
      for (int g = 0; g < 2; ++g) {
        float e[8];
        float sum = 0.f;
#pragma unroll
        for (int t = 0; t < 2; ++t)
#pragma unroll
          for (int r = 0; r < 4; ++r) {
            const float v = exp2f(sA[g][t][r]);  // bare v_exp_f32 (scale pre-folded)
            e[t * 4 + r] = v;
            sum += v;
          }
        l_part[g] += sum;
        union { f16x8 v8; fp16v2 p2[4]; } ap;
#pragma unroll
        for (int c = 0; c < 4; ++c)
          ap.p2[c] = __builtin_amdgcn_cvt_pkrtz(e[2 * c], e[2 * c + 1]);
#pragma unroll
        for (int n16 = 0; n16 < 4; ++n16)
          acc_o[g][n16] = __builtin_amdgcn_mfma_f32_16x16x32_f16(ap.v8, bvv[n16], acc_o[g][n16], 0, 0, 0);
      }
    }
  }
#pragma unroll
  for (int g = 0; g < 2; ++g) {
    float lp = l_part[g];
    lp += __shfl_xor(lp, 16);
    lp += __shfl_xor(lp, 32);
    f16* obase = out + ((size_t)b * NN + n0 + (wave + 4 * g) * 16) * HH + h * DH;
#pragma unroll
    for (int r = 0; r < 4; ++r) {
      const float lr = __shfl(lp, (lane & 48) | (quad * 4 + r));
      const float inv = 1.0f / lr;
#pragma unroll
      for (int n16 = 0; n16 < 4; ++n16)
        obase[(size_t)(quad * 4 + r) * HH + n16 * 16 + l16] = (f16)(acc_o[g][n16][r] * inv);
    }
  }
}

// ---------------------------------------------------------------------------

extern "C" void kernel_launch(void* const* d_in, const int* in_sizes, int n_in,
                              void* d_out, int out_size, void* d_ws, size_t ws_size,
                              hipStream_t stream) {
  const float* x     = (const float*)d_in[0];
  const int*   ei    = (const int*)d_in[1];
  const float* W_gcn = (const float*)d_in[2];
  const float* b_gcn = (const float*)d_in[3];
  const float* wi    = (const float*)d_in[4];
  const float* bi    = (const float*)d_in[5];
  const float* wo    = (const float*)d_in[6];
  const float* bo    = (const float*)d_in[7];
  const float* fcw   = (const float*)d_in[8];
  const float* fcb   = (const float*)d_in[9];
  float* out = (float*)d_out;
  const int E = in_sizes[1] / 2;  // 65536
  const int M = 4 * NN;           // 8192 rows

  char* wsb = (char*)d_ws;
  const size_t MB = 1u << 20;
  f16* xl16   = (f16*)(wsb + 4 * MB);         // 8 MB
  f16* hb16   = (f16*)(wsb + 12 * MB);        // 8 MB
  f16* Qb     = (f16*)(wsb + 20 * MB);        // 8 MB
  f16* Kb     = (f16*)(wsb + 28 * MB);        // 8 MB
  f16* Vb     = (f16*)(wsb + 36 * MB);        // 8 MB
  f16* attn16 = (f16*)(wsb + 44 * MB);        // 8 MB
  f16* proj16 = (f16*)(wsb + 52 * MB);        // 8 MB
  f16* wi16   = (f16*)(wsb + 60 * MB);        // 1.5 MB  [1536,512] (n,k)
  f16* wo16   = (f16*)(wsb + 62 * MB);        // 0.5 MB  [512,512]  (n,k)
  f16* wg16t  = (f16*)(wsb + 63 * MB);        // 0.25 MB [512,256]  (n,k)
  f16* fcw16t = (f16*)(wsb + 64 * MB);        // 0.25 MB [256,512]  (n,k)
  float* deg  = (float*)(wsb + 65 * MB);
  float* dinv = deg + NN;
  int* rowptr = (int*)(dinv + NN);
  int* cursor = rowptr + 2080;
  int* csr    = cursor + NN;                  // E ints

  // fused prep: converts + deg/cursor init (2 kernels)
  prep_cvt_kernel<<<1025, 256, 0, stream>>>(wi, wo, wi16, wo16, deg, cursor);
  prep_transpose_kernel<<<256, 256, 0, stream>>>(W_gcn, fcw, wg16t, fcw16t);

  // CSR build
  count_deg_kernel<<<(E + 255) / 256, 256, 0, stream>>>(ei, E, deg);
  build_rowptr_kernel<<<1, 1024, 0, stream>>>(deg, dinv, rowptr);
  fill_csr_kernel<<<(E + 255) / 256, 256, 0, stream>>>(ei, E, rowptr, cursor, csr);

  // xl = x @ W_gcn -> f16 (A staged f32->f16 in-kernel)  [8192,512]  MT=64
  mfma_gemm_kernel<1, false, false, true, 64><<<dim3(4, 128), 256, 0, stream>>>(
      x, wg16t, nullptr, xl16, M, 512, 256, nullptr, nullptr, nullptr);
  // h = GCN aggregate + b_gcn -> f16   [8192,512]
  gcn_aggregate_kernel<<<NN, 256, 0, stream>>>(xl16, dinv, rowptr, csr, b_gcn, hb16);
  // qkv = h @ wi^T + bi -> Q/K/V split f16 [bh][n][64], Q scaled (MT=128)
  mfma_gemm_kernel<2, true, false, false><<<dim3(12, 64), 256, 0, stream>>>(
      hb16, wi16, bi, nullptr, M, 1536, 512, Qb, Kb, Vb);
  // attention -> attn16                [8192,512]
  flash_attn_f16_kernel<<<dim3(NN / 128, 32), 256, 0, stream>>>(Qb, Kb, Vb, attn16);
  // proj = relu(attn @ wo^T + bo) -> f16  MT=64
  mfma_gemm_kernel<1, true, true, false, 64><<<dim3(4, 128), 256, 0, stream>>>(
      attn16, wo16, bo, proj16, M, 512, 512, nullptr, nullptr, nullptr);
  // out = proj @ fc_w + fc_b -> f32    [8192,256]  MT=64
  mfma_gemm_kernel<0, true, false, false, 64><<<dim3(2, 128), 256, 0, stream>>>(
      proj16, fcw16t, fcb, out, M, 256, 512, nullptr, nullptr, nullptr);
}

// Round 11
// 261.822 us; speedup vs baseline: 1.0080x; 1.0008x over previous
//
#include <hip/hip_runtime.h>
#include <hip/hip_bf16.h>

// ---------------------------------------------------------------------------
// GCNWithSelfAttention: GCNConv -> MHA(8 heads) -> ReLU -> Linear
// B=4, N=2048, Din=256, H=512, nh=8, dh=64, E=65536, Dout=256.
// Full f16-MFMA chain. Flash: S^T register-P, K=32 PV via sigma-permuted V,
// 2 q-blocks/wave, exp2 (scale pre-folded), reg-prefetch pipeline,
// XCD-swizzled block mapping (same bh -> same XCD for K/V L2 locality).
// ---------------------------------------------------------------------------

#define NN 2048
#define HH 512
#define NHEAD 8
#define DH 64

typedef _Float16 f16;
typedef __attribute__((ext_vector_type(2))) _Float16 f16x2;
typedef __attribute__((ext_vector_type(4))) _Float16 f16x4;
typedef __attribute__((ext_vector_type(8))) _Float16 f16x8;
typedef __attribute__((ext_vector_type(4))) float f32x4;

#define GLOAD_LDS16(g, l)                                              \
  __builtin_amdgcn_global_load_lds(                                    \
      (const __attribute__((address_space(1))) void*)(g),              \
      (__attribute__((address_space(3))) void*)(l), 16, 0, 0)

// ---------------- fused prep: wi/wo converts + deg/cursor init -------------

__global__ __launch_bounds__(256) void prep_cvt_kernel(const float* __restrict__ wi,
                                                       const float* __restrict__ wo,
                                                       f16* __restrict__ wi16,
                                                       f16* __restrict__ wo16,
                                                       float* __restrict__ deg,
                                                       int* __restrict__ cursor) {
  const int bid = blockIdx.x, t = threadIdx.x;
  if (bid < 768) {                       // wi: 1536*512 f32 = 196608 float4
    const int i = bid * 256 + t;
    const float4 v = ((const float4*)wi)[i];
    f16x4 o = { (f16)v.x, (f16)v.y, (f16)v.z, (f16)v.w };
    ((f16x4*)wi16)[i] = o;
  } else if (bid < 1024) {               // wo: 512*512 f32 = 65536 float4
    const int i = (bid - 768) * 256 + t;
    const float4 v = ((const float4*)wo)[i];
    f16x4 o = { (f16)v.x, (f16)v.y, (f16)v.z, (f16)v.w };
    ((f16x4*)wo16)[i] = o;
  } else {                               // deg/cursor init
    for (int i = t; i < NN; i += 256) { deg[i] = 1.0f; cursor[i] = 0; }
  }
}

// fused transpose-convert: wg [256,512]->[512,256], fcw [512,256]->[256,512]
__global__ __launch_bounds__(256) void prep_transpose_kernel(const float* __restrict__ wg,
                                                             const float* __restrict__ fcw,
                                                             f16* __restrict__ wg16t,
                                                             f16* __restrict__ fcw16t) {
  __shared__ float tbuf[32][33];
  const float* in;
  f16* outp;
  int R, C, bx, by;
  if (blockIdx.x < 128) { in = wg;  outp = wg16t;  R = 256; C = 512;
                          bx = blockIdx.x & 15; by = blockIdx.x >> 4; }
  else { int id = blockIdx.x - 128; in = fcw; outp = fcw16t; R = 512; C = 256;
         bx = id & 7; by = id >> 3; }
  const int c0 = bx * 32, r0 = by * 32;
  const int tx = threadIdx.x & 31, ty = threadIdx.x >> 5;
#pragma unroll
  for (int i = 0; i < 32; i += 8) tbuf[ty + i][tx] = in[(size_t)(r0 + ty + i) * C + c0 + tx];
  __syncthreads();
#pragma unroll
  for (int i = 0; i < 32; i += 8)
    outp[(size_t)(c0 + ty + i) * R + r0 + tx] = (f16)tbuf[tx][ty + i];
}

// ---------------- degree / CSR build ----------------

__global__ __launch_bounds__(256) void count_deg_kernel(const int* __restrict__ ei, int E,
                                                        float* __restrict__ deg) {
  int e = blockIdx.x * 256 + threadIdx.x;
  if (e < E) atomicAdd(&deg[ei[E + e]], 1.0f);  // dst row
}

__global__ __launch_bounds__(1024) void build_rowptr_kernel(const float* __restrict__ deg,
                                                            float* __restrict__ dinv,
                                                            int* __restrict__ rowptr) {
  __shared__ int a[NN];
  __shared__ int bbuf[NN];
  const int t = threadIdx.x;
  for (int i = t; i < NN; i += 1024) {
    float dg = deg[i];
    a[i] = (int)dg - 1;
    dinv[i] = rsqrtf(dg);
  }
  __syncthreads();
  int* src = a;
  int* dst = bbuf;
  for (int off = 1; off < NN; off <<= 1) {
    for (int i = t; i < NN; i += 1024) {
      int v = src[i];
      if (i >= off) v += src[i - off];
      dst[i] = v;
    }
    __syncthreads();
    int* tmp = src; src = dst; dst = tmp;
  }
  for (int i = t; i < NN; i += 1024) rowptr[i + 1] = src[i];
  if (t == 0) rowptr[0] = 0;
}

__global__ __launch_bounds__(256) void fill_csr_kernel(const int* __restrict__ ei, int E,
                                                       const int* __restrict__ rowptr,
                                                       int* __restrict__ cursor,
                                                       int* __restrict__ csr_src) {
  int e = blockIdx.x * 256 + threadIdx.x;
  if (e < E) {
    int s = ei[e];
    int d = ei[E + e];
    int pos = atomicAdd(&cursor[d], 1);
    csr_src[rowptr[d] + pos] = s;
  }
}

// ---------------- f16 MFMA GEMM: C[M,N] = A[M,K] * Bt[N,K]^T (+bias)(+relu) -
// MTxN128 tile, BK=32, 256 thr = 4 waves; MT=128: wave=64x64 (4x4 mfma),
// MT=64: wave=32x64 (2x4). OUTMODE: 0 f32 [M,N]; 1 f16 [M,N]; 2 qkv split.
// AF32: A is f32, converted during staging.

template <int OUTMODE, bool BIAS, bool RELU, bool AF32, int MT = 128>
__global__ __launch_bounds__(256) void mfma_gemm_kernel(
    const void* __restrict__ Ap, const f16* __restrict__ Bt,
    const float* __restrict__ bias, void* __restrict__ Cout,
    int M, int N, int K,
    f16* __restrict__ q_out, f16* __restrict__ k_out, f16* __restrict__ v_out) {
  constexpr int MI = MT / 32;  // 16-row blocks per wave in M
  __shared__ f16 As[MT * 32];
  __shared__ f16 Bs[128 * 32];
  const int tid = threadIdx.x;
  const int wave = tid >> 6, lane = tid & 63;
  const int quad = lane >> 4, l16 = lane & 15;
  const int m0 = blockIdx.y * MT, n0 = blockIdx.x * 128;
  const int moff = (wave >> 1) * (MI * 16), noff = (wave & 1) * 64;

  f32x4 acc[MI][4];
#pragma unroll
  for (int i = 0; i < MI; ++i)
#pragma unroll
    for (int j = 0; j < 4; ++j) acc[i][j] = (f32x4){0.f, 0.f, 0.f, 0.f};

  const int rpw = MT / 4;  // A rows staged per wave
  const int srowA = rpw * wave + (lane >> 2);
  const int srowB = 32 * wave + (lane >> 2);
  const int kch = (lane & 3) * 8;
  const f16* Ag = (const f16*)Ap + (size_t)(m0 + srowA) * K + kch;
  const float* Ag32 = (const float*)Ap + (size_t)(m0 + srowA) * K + kch;
  const f16* Bg = Bt + (size_t)(n0 + srowB) * K + kch;
  f16* As_w = &As[(rpw * wave) * 32];
  f16* Bs_w = &Bs[(32 * wave) * 32];

  for (int k0 = 0; k0 < K; k0 += 32) {
    __syncthreads();
    if (AF32) {
#pragma unroll
      for (int t = 0; t < (MT == 128 ? 2 : 1); ++t) {
        const float* g = Ag32 + k0 + (size_t)(16 * t) * K;
        const float4 u0 = *(const float4*)g;
        const float4 u1 = *(const float4*)(g + 4);
        f16x8 o = { (f16)u0.x, (f16)u0.y, (f16)u0.z, (f16)u0.w,
                    (f16)u1.x, (f16)u1.y, (f16)u1.z, (f16)u1.w };
        *(f16x8*)&As[(srowA + 16 * t) * 32 + kch] = o;
      }
    } else {
      GLOAD_LDS16(Ag + k0, As_w);
      if (MT == 128) GLOAD_LDS16(Ag + k0 + (size_t)16 * K, As_w + 16 * 32);
    }
    GLOAD_LDS16(Bg + k0, Bs_w);
    GLOAD_LDS16(Bg + k0 + (size_t)16 * K, Bs_w + 16 * 32);
    __syncthreads();
    f16x8 af[MI], bf[4];
#pragma unroll
    for (int m16 = 0; m16 < MI; ++m16)
      af[m16] = *(const f16x8*)&As[(moff + m16 * 16 + l16) * 32 + quad * 8];
#pragma unroll
    for (int n16 = 0; n16 < 4; ++n16)
      bf[n16] = *(const f16x8*)&Bs[(noff + n16 * 16 + l16) * 32 + quad * 8];
#pragma unroll
    for (int m16 = 0; m16 < MI; ++m16)
#pragma unroll
      for (int n16 = 0; n16 < 4; ++n16)
        acc[m16][n16] =
            __builtin_amdgcn_mfma_f32_16x16x32_f16(af[m16], bf[n16], acc[m16][n16], 0, 0, 0);
  }

  float bv[4];
#pragma unroll
  for (int n16 = 0; n16 < 4; ++n16)
    bv[n16] = BIAS ? bias[n0 + noff + n16 * 16 + l16] : 0.f;

  if (OUTMODE == 2) {
    const int hblk = (n0 >> 6) + (wave & 1);
    const int which = hblk >> 3, h = hblk & 7;
    f16* dst = (which == 0) ? q_out : (which == 1) ? k_out : v_out;
    // Q pre-scale folds dh^-0.5 AND log2(e) so flash can use bare exp2.
    const float scale = (which == 0) ? 0.125f * 1.44269504f : 1.0f;
#pragma unroll
    for (int m16 = 0; m16 < MI; ++m16) {
#pragma unroll
      for (int r = 0; r < 4; ++r) {
        const int m = m0 + moff + m16 * 16 + quad * 4 + r;
        const int b = m >> 11, ns = m & 2047;
        f16* row = dst + ((size_t)(b * 8 + h) * NN + ns) * DH;
#pragma unroll
        for (int n16 = 0; n16 < 4; ++n16) {
          const int d = n16 * 16 + l16;
          row[d] = (f16)((acc[m16][n16][r] + bv[n16]) * scale);
        }
      }
    }
  } else {
#pragma unroll
    for (int m16 = 0; m16 < MI; ++m16) {
#pragma unroll
      for (int r = 0; r < 4; ++r) {
        const size_t row = (size_t)(m0 + moff + m16 * 16 + quad * 4 + r) * N;
#pragma unroll
        for (int n16 = 0; n16 < 4; ++n16) {
          const int col = n0 + noff + n16 * 16 + l16;
          float v = acc[m16][n16][r] + bv[n16];
          if (RELU) v = fmaxf(v, 0.f);
          if (OUTMODE == 0) ((float*)Cout)[row + col] = v;
          else ((f16*)Cout)[row + col] = (f16)v;
        }
      }
    }
  }
}

// ---------------- GCN aggregation (CSR gather; thread = batch x octet) -----

__global__ __launch_bounds__(256) void gcn_aggregate_kernel(const f16* __restrict__ xl,
                                                            const float* __restrict__ dinv,
                                                            const int* __restrict__ rowptr,
                                                            const int* __restrict__ csr_src,
                                                            const float* __restrict__ b_gcn,
                                                            f16* __restrict__ out) {
  __shared__ int s_src[256];
  __shared__ float s_dv[256];
  const int i = blockIdx.x;            // node, shared by all 4 batches
  const int tid = threadIdx.x;
  const int b = tid >> 6;              // batch
  const int f = (tid & 63) * 8;        // feature octet
  const float dv_i = dinv[i];
  const f16* xb = xl + (size_t)b * NN * HH;
  float acc[8];
  {
    const f16x8 self = *(const f16x8*)&xb[(size_t)i * HH + f];
#pragma unroll
    for (int c = 0; c < 8; ++c) acc[c] = (float)self[c] * dv_i;
  }
  const int beg = rowptr[i], end = rowptr[i + 1];
  for (int c0 = beg; c0 < end; c0 += 256) {
    const int cnt = min(256, end - c0);
    __syncthreads();
    if (tid < cnt) {
      int s = csr_src[c0 + tid];
      s_src[tid] = s;
      s_dv[tid] = dinv[s];
    }
    __syncthreads();
    for (int t = 0; t < cnt; ++t) {
      const f16x8 v = *(const f16x8*)&xb[(size_t)s_src[t] * HH + f];
      const float w = s_dv[t];
#pragma unroll
      for (int c = 0; c < 8; ++c) acc[c] = fmaf((float)v[c], w, acc[c]);
    }
  }
  const float4 bg0 = *(const float4*)&b_gcn[f];
  const float4 bg1 = *(const float4*)&b_gcn[f + 4];
  f16x8 o;
  o[0] = (f16)(acc[0] * dv_i + bg0.x);
  o[1] = (f16)(acc[1] * dv_i + bg0.y);
  o[2] = (f16)(acc[2] * dv_i + bg0.z);
  o[3] = (f16)(acc[3] * dv_i + bg0.w);
  o[4] = (f16)(acc[4] * dv_i + bg1.x);
  o[5] = (f16)(acc[5] * dv_i + bg1.y);
  o[6] = (f16)(acc[6] * dv_i + bg1.z);
  o[7] = (f16)(acc[7] * dv_i + bg1.w);
  *(f16x8*)&out[((size_t)b * NN + i) * HH + f] = o;
}

// ---------------- flash attention v6b -------------------------------------
// Q/K/V: f16 [bh][n][64]; Q pre-scaled by 0.125*log2e. Block = 4 waves,
// q-tile 128 (wave w owns q-16-blocks w, w+4). K-tile 128.
// S^T = K*Q^T; register P (element-insert pack, SROA-friendly);
// PV at K=32 via sigma-permuted V rows. Register prefetch of next K/V tile.
// K staging: krow=tid>>1, kcol=(tid&1)*32, FOUR b128 chunks (+0,+8,+16,+24)
// -> full 128x64 coverage (r10 bug: only 2 chunks = half tile).
// XCD swizzle: lin%32 = bh so all q-tiles of one bh share an XCD L2.

__global__ __launch_bounds__(256) void flash_attn_f16_kernel(const f16* __restrict__ Qb,
                                                             const f16* __restrict__ Kb,
                                                             const f16* __restrict__ Vb,
                                                             f16* __restrict__ out) {
  const int LDK = 72;   // dword stride 36 -> b128 frag reads uniform-8 (floor)
  const int LDV = 136;  // dword stride 68 -> b128 frag reads uniform-8 (floor)
  __shared__ f16 Ks[128 * LDK];   // 18.4 KB
  __shared__ f16 Vt[64 * LDV];    // 17.4 KB
  const int tid = threadIdx.x;
  const int wave = tid >> 6, lane = tid & 63;
  const int quad = lane >> 4, l16 = lane & 15;
  const int lin = blockIdx.x + 16 * blockIdx.y;  // grid (16,32), 512 blocks
  const int bh = lin & 31;                       // same bh -> same XCD (mod-8 dispatch)
  const int n0 = (lin >> 5) * 128;
  const int b = bh >> 3, h = bh & 7;
  const f16* kb = Kb + (size_t)bh * NN * DH;
  const f16* vb = Vb + (size_t)bh * NN * DH;

  f16x8 aq[2][2];
#pragma unroll
  for (int g = 0; g < 2; ++g) {
    const f16* qf = Qb + ((size_t)bh * NN + n0 + (wave + 4 * g) * 16 + l16) * DH + quad * 8;
    aq[g][0] = *(const f16x8*)qf;
    aq[g][1] = *(const f16x8*)(qf + 32);
  }

  float l_part[2] = {0.f, 0.f};
  f32x4 acc_o[2][4];
#pragma unroll
  for (int g = 0; g < 2; ++g)
#pragma unroll
    for (int n16 = 0; n16 < 4; ++n16) acc_o[g][n16] = (f32x4){0.f, 0.f, 0.f, 0.f};

  const int vdg = tid & 15, jbb = tid >> 4;
  const int krow = tid >> 1, kcol = (tid & 1) * 32;  // 2 thr/row, 32 f16 each

  // register prefetch buffers (+~48 VGPR)
  f16x8 kreg[4];
  f16x4 vreg[2][4];
  // prologue: load tile 0 (K: 4 b128 chunks -> full 32 cols per thread)
#pragma unroll
  for (int i = 0; i < 4; ++i)
    kreg[i] = *(const f16x8*)(kb + (size_t)krow * DH + kcol + 8 * i);
#pragma unroll
  for (int cc = 0; cc < 2; ++cc) {
    const int jb = jbb + 16 * cc;
#pragma unroll
    for (int i = 0; i < 4; ++i)
      vreg[cc][i] = *(const f16x4*)(vb + (size_t)(jb * 4 + i) * DH + vdg * 4);
  }

  for (int kt = 0; kt < NN / 128; ++kt) {
    __syncthreads();
    // write staged tile from regs to LDS
#pragma unroll
    for (int i = 0; i < 4; ++i)
      *(f16x8*)&Ks[krow * LDK + kcol + 8 * i] = kreg[i];
#pragma unroll
    for (int cc = 0; cc < 2; ++cc) {
      const int jb = jbb + 16 * cc;
      const int sb4 = (jb >> 3) * 32 + (jb & 3) * 8 + ((jb >> 2) & 1) * 4;
#pragma unroll
      for (int c = 0; c < 4; ++c) {
        f16x4 o = { vreg[cc][0][c], vreg[cc][1][c], vreg[cc][2][c], vreg[cc][3][c] };
        *(f16x4*)&Vt[(vdg * 4 + c) * LDV + sb4] = o;
      }
    }
    // issue next tile's loads (in flight across the compute below)
    if (kt + 1 < NN / 128) {
      const int k1 = (kt + 1) * 128;
#pragma unroll
      for (int i = 0; i < 4; ++i)
        kreg[i] = *(const f16x8*)(kb + (size_t)(k1 + krow) * DH + kcol + 8 * i);
#pragma unroll
      for (int cc = 0; cc < 2; ++cc) {
        const int jb = jbb + 16 * cc;
#pragma unroll
        for (int i = 0; i < 4; ++i)
          vreg[cc][i] = *(const f16x4*)(vb + (size_t)(k1 + jb * 4 + i) * DH + vdg * 4);
      }
    }
    __syncthreads();
    // per 32-col group p: 2 S^T tiles x 2 q-blocks -> register P -> K=32 PV
#pragma unroll
    for (int p = 0; p < 4; ++p) {
      f32x4 sA[2][2];  // [g][t]
#pragma unroll
      for (int t = 0; t < 2; ++t) {
        const f16x8 ak0 = *(const f16x8*)&Ks[(p * 32 + t * 16 + l16) * LDK + quad * 8];
        const f16x8 ak1 = *(const f16x8*)&Ks[(p * 32 + t * 16 + l16) * LDK + quad * 8 + 32];
#pragma unroll
        for (int g = 0; g < 2; ++g) {
          f32x4 s = {0.f, 0.f, 0.f, 0.f};
          s = __builtin_amdgcn_mfma_f32_16x16x32_f16(ak0, aq[g][0], s, 0, 0, 0);
          s = __builtin_amdgcn_mfma_f32_16x16x32_f16(ak1, aq[g][1], s, 0, 0, 0);
          sA[g][t] = s;
        }
      }
      f16x8 bvv[4];
#pragma unroll
      for (int n16 = 0; n16 < 4; ++n16)
        bvv[n16] = *(const f16x8*)&Vt[(n16 * 16 + l16) * LDV + p * 32 + quad * 8];
#pragma unroll
      for (int g = 0; g < 2; ++g) {
        f16x8 ap;
        float sum = 0.f;
#pragma unroll
        for (int t = 0; t < 2; ++t)
#pragma unroll
          for (int r = 0; r < 4; ++r) {
            const float v = exp2f(sA[g][t][r]);  // bare v_exp_f32 (scale pre-folded)
            sum += v;
            ap[t * 4 + r] = (f16)v;
          }
        l_part[g] += sum;
#pragma unroll
        for (int n16 = 0; n16 < 4; ++n16)
          acc_o[g][n16] = __builtin_amdgcn_mfma_f32_16x16x32_f16(ap, bvv[n16], acc_o[g][n16], 0, 0, 0);
      }
    }
  }
#pragma unroll
  for (int g = 0; g < 2; ++g) {
    float lp = l_part[g];
    lp += __shfl_xor(lp, 16);
    lp += __shfl_xor(lp, 32);
    f16* obase = out + ((size_t)b * NN + n0 + (wave + 4 * g) * 16) * HH + h * DH;
#pragma unroll
    for (int r = 0; r < 4; ++r) {
      const float lr = __shfl(lp, (lane & 48) | (quad * 4 + r));
      const float inv = 1.0f / lr;
#pragma unroll
      for (int n16 = 0; n16 < 4; ++n16)
        obase[(size_t)(quad * 4 + r) * HH + n16 * 16 + l16] = (f16)(acc_o[g][n16][r] * inv);
    }
  }
}

// ---------------------------------------------------------------------------

extern "C" void kernel_launch(void* const* d_in, const int* in_sizes, int n_in,
                              void* d_out, int out_size, void* d_ws, size_t ws_size,
                              hipStream_t stream) {
  const float* x     = (const float*)d_in[0];
  const int*   ei    = (const int*)d_in[1];
  const float* W_gcn = (const float*)d_in[2];
  const float* b_gcn = (const float*)d_in[3];
  const float* wi    = (const float*)d_in[4];
  const float* bi    = (const float*)d_in[5];
  const float* wo    = (const float*)d_in[6];
  const float* bo    = (const float*)d_in[7];
  const float* fcw   = (const float*)d_in[8];
  const float* fcb   = (const float*)d_in[9];
  float* out = (float*)d_out;
  const int E = in_sizes[1] / 2;  // 65536
  const int M = 4 * NN;           // 8192 rows

  char* wsb = (char*)d_ws;
  const size_t MB = 1u << 20;
  f16* xl16   = (f16*)(wsb + 4 * MB);         // 8 MB
  f16* hb16   = (f16*)(wsb + 12 * MB);        // 8 MB
  f16* Qb     = (f16*)(wsb + 20 * MB);        // 8 MB
  f16* Kb     = (f16*)(wsb + 28 * MB);        // 8 MB
  f16* Vb     = (f16*)(wsb + 36 * MB);        // 8 MB
  f16* attn16 = (f16*)(wsb + 44 * MB);        // 8 MB
  f16* proj16 = (f16*)(wsb + 52 * MB);        // 8 MB
  f16* wi16   = (f16*)(wsb + 60 * MB);        // 1.5 MB  [1536,512] (n,k)
  f16* wo16   = (f16*)(wsb + 62 * MB);        // 0.5 MB  [512,512]  (n,k)
  f16* wg16t  = (f16*)(wsb + 63 * MB);        // 0.25 MB [512,256]  (n,k)
  f16* fcw16t = (f16*)(wsb + 64 * MB);        // 0.25 MB [256,512]  (n,k)
  float* deg  = (float*)(wsb + 65 * MB);
  float* dinv = deg + NN;
  int* rowptr = (int*)(dinv + NN);
  int* cursor = rowptr + 2080;
  int* csr    = cursor + NN;                  // E ints

  // fused prep: converts + deg/cursor init (2 kernels)
  prep_cvt_kernel<<<1025, 256, 0, stream>>>(wi, wo, wi16, wo16, deg, cursor);
  prep_transpose_kernel<<<256, 256, 0, stream>>>(W_gcn, fcw, wg16t, fcw16t);

  // CSR build
  count_deg_kernel<<<(E + 255) / 256, 256, 0, stream>>>(ei, E, deg);
  build_rowptr_kernel<<<1, 1024, 0, stream>>>(deg, dinv, rowptr);
  fill_csr_kernel<<<(E + 255) / 256, 256, 0, stream>>>(ei, E, rowptr, cursor, csr);

  // xl = x @ W_gcn -> f16 (A staged f32->f16 in-kernel)  [8192,512]  MT=64
  mfma_gemm_kernel<1, false, false, true, 64><<<dim3(4, 128), 256, 0, stream>>>(
      x, wg16t, nullptr, xl16, M, 512, 256, nullptr, nullptr, nullptr);
  // h = GCN aggregate + b_gcn -> f16   [8192,512]
  gcn_aggregate_kernel<<<NN, 256, 0, stream>>>(xl16, dinv, rowptr, csr, b_gcn, hb16);
  // qkv = h @ wi^T + bi -> Q/K/V split f16 [bh][n][64], Q scaled (MT=128)
  mfma_gemm_kernel<2, true, false, false><<<dim3(12, 64), 256, 0, stream>>>(
      hb16, wi16, bi, nullptr, M, 1536, 512, Qb, Kb, Vb);
  // attention -> attn16                [8192,512]
  flash_attn_f16_kernel<<<dim3(16, 32), 256, 0, stream>>>(Qb, Kb, Vb, attn16);
  // proj = relu(attn @ wo^T + bo) -> f16  MT=64
  mfma_gemm_kernel<1, true, true, false, 64><<<dim3(4, 128), 256, 0, stream>>>(
      attn16, wo16, bo, proj16, M, 512, 512, nullptr, nullptr, nullptr);
  // out = proj @ fc_w + fc_b -> f32    [8192,256]  MT=64
  mfma_gemm_kernel<0, true, false, false, 64><<<dim3(2, 128), 256, 0, stream>>>(
      proj16, fcw16t, fcb, out, M, 256, 512, nullptr, nullptr, nullptr);
}